// Round 1
// baseline (2591.422 us; speedup 1.0000x reference)
//
#include <hip/hip_runtime.h>
#include <cstdint>
#include <cstddef>

#define SEQ 4096
#define DM  2048

// Dropout mask variant:
// 0 = partitionable threefry (JAX >= 0.4.36 default): bits = o0 ^ o1, counter = (0, idx)
// 1 = original threefry counter mode: split-in-half counters
// 2 = partitionable, bits = o1 (lo word)
// 3 = partitionable, bits = o0 (hi word)
#define DROPOUT_VARIANT 0

typedef unsigned int u32;

__device__ __forceinline__ u32 rotl32(u32 x, int r) { return (x << r) | (x >> (32 - r)); }

// Threefry-2x32, 20 rounds, key = (0, 42)  [jax.random.key(42)]
__device__ __forceinline__ void tf2x32(u32 c0, u32 c1, u32& o0, u32& o1) {
  const u32 k0 = 0u, k1 = 42u, k2 = 0x1BD11BDAu ^ 0u ^ 42u;
  u32 x0 = c0 + k0;
  u32 x1 = c1 + k1;
#define TFR(r) { x0 += x1; x1 = rotl32(x1, (r)); x1 ^= x0; }
  TFR(13) TFR(15) TFR(26) TFR(6)   x0 += k1; x1 += k2 + 1u;
  TFR(17) TFR(29) TFR(16) TFR(24)  x0 += k2; x1 += k0 + 2u;
  TFR(13) TFR(15) TFR(26) TFR(6)   x0 += k0; x1 += k1 + 3u;
  TFR(17) TFR(29) TFR(16) TFR(24)  x0 += k1; x1 += k2 + 4u;
  TFR(13) TFR(15) TFR(26) TFR(6)   x0 += k2; x1 += k0 + 5u;
#undef TFR
  o0 = x0; o1 = x1;
}

__device__ __forceinline__ u32 dropout_bits(u32 idx) {
#if DROPOUT_VARIANT == 0
  u32 a, b; tf2x32(0u, idx, a, b); return a ^ b;
#elif DROPOUT_VARIANT == 1
  const u32 HALF = ((u32)SEQ * (u32)SEQ) / 2u;
  u32 a, b;
  if (idx < HALF) { tf2x32(idx, idx + HALF, a, b); return a; }
  else            { tf2x32(idx - HALF, idx, a, b); return b; }
#elif DROPOUT_VARIANT == 2
  u32 a, b; tf2x32(0u, idx, a, b); return b;
#else
  u32 a, b; tf2x32(0u, idx, a, b); return a;
#endif
}

// keep iff uniform = bitcast((bits>>9)|0x3F800000) - 1 < 0.5  <=>  top bit of bits == 0
__device__ __forceinline__ bool dropout_keep(u32 idx) {
  return (dropout_bits(idx) & 0x80000000u) == 0u;
}

// ---------------------------------------------------------------------------
// fp32 tiled GEMM core. C[128x128] block at (rowBlock, colBlock).
// A: row-major, stride = K.  TRANSB=false: B row-major KxN (stride ldb).
// TRANSB=true: B row-major NxK (stride K), computes A*B^T.
// 256 threads, 8x8 micro-tile in 4+4 split. BK=16.
// ---------------------------------------------------------------------------
template <bool TRANSB, bool DIV_SCALE>
__device__ __forceinline__ void gemm_core(
    const float* __restrict__ A, const float* __restrict__ Bm,
    float* __restrict__ C, int K, int ldb, int ldc,
    int rowBlock, int colBlock, int kmax)
{
  __shared__ float As[16][132];
  __shared__ float Bs[16][132];
  const int tid = threadIdx.x;
  const int tn = tid & 15;
  const int tm = tid >> 4;

  float acc[8][8];
#pragma unroll
  for (int i = 0; i < 8; ++i)
#pragma unroll
    for (int j = 0; j < 8; ++j) acc[i][j] = 0.f;

  for (int kb = 0; kb < kmax; kb += 16) {
    // stage A tile (128 rows x 16 k), transposed into As[k][m]
#pragma unroll
    for (int t = 0; t < 2; ++t) {
      int f = tid + t * 256;
      int m = f >> 2;
      int kc = (f & 3) << 2;
      const float4 v = *(const float4*)(A + (size_t)(rowBlock + m) * K + kb + kc);
      As[kc + 0][m] = v.x; As[kc + 1][m] = v.y; As[kc + 2][m] = v.z; As[kc + 3][m] = v.w;
    }
    if (TRANSB) {
      // B is NxK row-major: Bs[k][n] = B[(colBlock+n)*K + kb+k]
#pragma unroll
      for (int t = 0; t < 2; ++t) {
        int f = tid + t * 256;
        int n = f >> 2;
        int kc = (f & 3) << 2;
        const float4 v = *(const float4*)(Bm + (size_t)(colBlock + n) * K + kb + kc);
        Bs[kc + 0][n] = v.x; Bs[kc + 1][n] = v.y; Bs[kc + 2][n] = v.z; Bs[kc + 3][n] = v.w;
      }
    } else {
      // B is KxN row-major: Bs[k][n] = B[(kb+k)*ldb + colBlock+n]
#pragma unroll
      for (int t = 0; t < 2; ++t) {
        int f = tid + t * 256;
        int n4 = f & 31;
        int kr = f >> 5;
        const float4 v = *(const float4*)(Bm + (size_t)(kb + kr) * ldb + colBlock + (n4 << 2));
        *(float4*)&Bs[kr][n4 << 2] = v;
      }
    }
    __syncthreads();

#pragma unroll
    for (int kk = 0; kk < 16; ++kk) {
      const float4 a0 = *(const float4*)&As[kk][tm << 2];
      const float4 a1 = *(const float4*)&As[kk][(tm << 2) + 64];
      const float4 b0 = *(const float4*)&Bs[kk][tn << 2];
      const float4 b1 = *(const float4*)&Bs[kk][(tn << 2) + 64];
      float aa[8] = {a0.x, a0.y, a0.z, a0.w, a1.x, a1.y, a1.z, a1.w};
      float bb[8] = {b0.x, b0.y, b0.z, b0.w, b1.x, b1.y, b1.z, b1.w};
#pragma unroll
      for (int i = 0; i < 8; ++i)
#pragma unroll
        for (int j = 0; j < 8; ++j)
          acc[i][j] = fmaf(aa[i], bb[j], acc[i][j]);
    }
    __syncthreads();
  }

  const float scale = sqrtf(2048.0f);  // matches jnp.sqrt(float32(2048))
#pragma unroll
  for (int i = 0; i < 8; ++i) {
    int row = rowBlock + (tm << 2) + (i & 3) + ((i >> 2) << 6);
#pragma unroll
    for (int bg = 0; bg < 2; ++bg) {
      int col = colBlock + (tn << 2) + (bg << 6);
      float4 o;
      o.x = acc[i][bg * 4 + 0]; o.y = acc[i][bg * 4 + 1];
      o.z = acc[i][bg * 4 + 2]; o.w = acc[i][bg * 4 + 3];
      if (DIV_SCALE) { o.x /= scale; o.y /= scale; o.z /= scale; o.w /= scale; }
      *(float4*)(C + (size_t)row * ldc + col) = o;
    }
  }
}

// Q/K/V projections: z in {0,1,2} selects the weight/output pair.
__global__ __launch_bounds__(256) void k_proj(
    const float* __restrict__ X,
    const float* __restrict__ Wq, const float* __restrict__ Wk, const float* __restrict__ Wv,
    float* __restrict__ Q, float* __restrict__ Km, float* __restrict__ V)
{
  const float* B = (blockIdx.z == 0) ? Wq : (blockIdx.z == 1) ? Wk : Wv;
  float* C = (blockIdx.z == 0) ? Q : (blockIdx.z == 1) ? Km : V;
  gemm_core<false, false>(X, B, C, DM, DM, DM, blockIdx.y * 128, blockIdx.x * 128, DM);
}

// S = (Q @ K^T) / sqrt(d); only lower-triangular 128x128 blocks.
__global__ __launch_bounds__(256) void k_scores(
    const float* __restrict__ Q, const float* __restrict__ Km, float* __restrict__ S)
{
  int by = blockIdx.y, bx = blockIdx.x;
  if (bx > by) return;
  gemm_core<true, true>(Q, Km, S, DM, 0, SEQ, by * 128, bx * 128, DM);
}

// Row softmax (causal) + inverted dropout, in place (S -> P).
__global__ __launch_bounds__(256) void k_softmax_dropout(float* __restrict__ S) {
  const int row = blockIdx.x;
  const int n = row + 1;  // valid entries j <= row
  const int tid = threadIdx.x;
  __shared__ float buf[SEQ];
  __shared__ float red[4];
  __shared__ float bcast;
  float* srow = S + (size_t)row * SEQ;

  float lmax = -INFINITY;
#pragma unroll
  for (int t = 0; t < 4; ++t) {
    int j4 = tid + t * 256;
    float4 v = *(const float4*)(srow + (size_t)j4 * 4);
    int b = j4 * 4;
    float x0 = (b + 0 < n) ? v.x : -INFINITY;
    float x1 = (b + 1 < n) ? v.y : -INFINITY;
    float x2 = (b + 2 < n) ? v.z : -INFINITY;
    float x3 = (b + 3 < n) ? v.w : -INFINITY;
    buf[b + 0] = x0; buf[b + 1] = x1; buf[b + 2] = x2; buf[b + 3] = x3;
    lmax = fmaxf(lmax, fmaxf(fmaxf(x0, x1), fmaxf(x2, x3)));
  }
  for (int off = 32; off > 0; off >>= 1) lmax = fmaxf(lmax, __shfl_down(lmax, off, 64));
  if ((tid & 63) == 0) red[tid >> 6] = lmax;
  __syncthreads();
  if (tid == 0) bcast = fmaxf(fmaxf(red[0], red[1]), fmaxf(red[2], red[3]));
  __syncthreads();
  const float m = bcast;

  float lsum = 0.f;
#pragma unroll
  for (int t = 0; t < 4; ++t) {
    int b = (tid + t * 256) * 4;
    float e0 = expf(buf[b + 0] - m);
    float e1 = expf(buf[b + 1] - m);
    float e2 = expf(buf[b + 2] - m);
    float e3 = expf(buf[b + 3] - m);
    buf[b + 0] = e0; buf[b + 1] = e1; buf[b + 2] = e2; buf[b + 3] = e3;
    lsum += (e0 + e1) + (e2 + e3);
  }
  for (int off = 32; off > 0; off >>= 1) lsum += __shfl_down(lsum, off, 64);
  if ((tid & 63) == 0) red[tid >> 6] = lsum;
  __syncthreads();
  if (tid == 0) bcast = (red[0] + red[1]) + (red[2] + red[3]);
  __syncthreads();
  const float total = bcast;

  // write P; zero the tail up to the 128-block boundary so PV can read full tiles
  const int zeroEnd = ((row >> 7) + 1) << 7;
  for (int j = tid; j < zeroEnd; j += 256) {
    float out = 0.f;
    if (j < n) {
      float w = buf[j] / total;
      out = dropout_keep((u32)(row * SEQ + j)) ? w * 2.0f : 0.f;
    }
    srow[j] = out;
  }
}

// context = P @ V, K-loop truncated at the causal boundary.
__global__ __launch_bounds__(256) void k_pv(
    const float* __restrict__ P, const float* __restrict__ V, float* __restrict__ O)
{
  int by = blockIdx.y;
  gemm_core<false, false>(P, V, O, SEQ, DM, DM, by * 128, blockIdx.x * 128, (by + 1) * 128);
}

extern "C" void kernel_launch(void* const* d_in, const int* in_sizes, int n_in,
                              void* d_out, int out_size, void* d_ws, size_t ws_size,
                              hipStream_t stream) {
  const float* x  = (const float*)d_in[0];
  const float* Wq = (const float*)d_in[1];
  const float* Wk = (const float*)d_in[2];
  const float* Wv = (const float*)d_in[3];
  float* ws = (float*)d_ws;

  const size_t NPROJ = (size_t)SEQ * DM;  // 8388608
  float* Q  = ws;
  float* Km = ws + NPROJ;
  float* V  = ws + 2 * NPROJ;
  float* S  = ws + 3 * NPROJ;             // 4096*4096, reused in place as P

  dim3 blk(256);
  k_proj<<<dim3(DM / 128, SEQ / 128, 3), blk, 0, stream>>>(x, Wq, Wk, Wv, Q, Km, V);
  k_scores<<<dim3(SEQ / 128, SEQ / 128), blk, 0, stream>>>(Q, Km, S);
  k_softmax_dropout<<<dim3(SEQ), blk, 0, stream>>>(S);
  k_pv<<<dim3(DM / 128, SEQ / 128), blk, 0, stream>>>(S, V, (float*)d_out);
}

// Round 2
// 704.352 us; speedup vs baseline: 3.6792x; 3.6792x over previous
//
#include <hip/hip_runtime.h>
#include <cstdint>
#include <cstddef>
#include <cmath>

#define SEQ 4096
#define DM  2048

typedef unsigned int u32;
typedef unsigned short u16;
typedef __attribute__((ext_vector_type(8))) short bf16x8;
typedef __attribute__((ext_vector_type(4))) float f32x4;

// ---------------- bf16 helpers (RNE) ----------------
__device__ __forceinline__ u16 f2bf(float f) {
  u32 u = __float_as_uint(f);
  return (u16)((u + 0x7FFFu + ((u >> 16) & 1u)) >> 16);
}
__device__ __forceinline__ float bf2f(u16 h) { return __uint_as_float(((u32)h) << 16); }

// ---------------- threefry dropout (verified round 1, variant 0) ----------------
__device__ __forceinline__ u32 rotl32(u32 x, int r) { return (x << r) | (x >> (32 - r)); }

__device__ __forceinline__ void tf2x32(u32 c0, u32 c1, u32& o0, u32& o1) {
  const u32 k0 = 0u, k1 = 42u, k2 = 0x1BD11BDAu ^ 0u ^ 42u;
  u32 x0 = c0 + k0;
  u32 x1 = c1 + k1;
#define TFR(r) { x0 += x1; x1 = rotl32(x1, (r)); x1 ^= x0; }
  TFR(13) TFR(15) TFR(26) TFR(6)   x0 += k1; x1 += k2 + 1u;
  TFR(17) TFR(29) TFR(16) TFR(24)  x0 += k2; x1 += k0 + 2u;
  TFR(13) TFR(15) TFR(26) TFR(6)   x0 += k0; x1 += k1 + 3u;
  TFR(17) TFR(29) TFR(16) TFR(24)  x0 += k1; x1 += k2 + 4u;
  TFR(13) TFR(15) TFR(26) TFR(6)   x0 += k2; x1 += k0 + 5u;
#undef TFR
  o0 = x0; o1 = x1;
}

__device__ __forceinline__ bool dropout_keep(u32 idx) {
  u32 a, b; tf2x32(0u, idx, a, b);
  return (((a ^ b) & 0x80000000u) == 0u);
}

// ---------------- async global -> LDS, 16 B/lane ----------------
__device__ __forceinline__ void g2l16(const void* g, void* l) {
  __builtin_amdgcn_global_load_lds((const __attribute__((address_space(1))) u32*)g,
                                   (__attribute__((address_space(3))) u32*)l, 16, 0, 0);
}

#define MFMA16(a, b, c) __builtin_amdgcn_mfma_f32_16x16x32_bf16(a, b, c, 0, 0, 0)

// ---------------------------------------------------------------------------
// MFMA GEMM core: C[128x128] = A * B^T.
// A planes: bf16 row-major [*][lda], tile rows rowBlock..+128, k contiguous.
// B planes: bf16 row-major [*][ldb], tile rows colBlock..+128, k contiguous.
// SPLIT: fp32 emulation via hi/lo bf16 planes (3 MFMAs per tile pair).
// 256 threads = 4 waves in 2x2; each wave owns a 64x64 quadrant (4x4 tiles
// of 16x16x32). Staging via global_load_lds width 16 (m97 structure).
// ---------------------------------------------------------------------------
template <bool SPLIT>
__device__ __forceinline__ void gemm_core(
    const u16* __restrict__ Ah, const u16* __restrict__ Al,
    const u16* __restrict__ Bh, const u16* __restrict__ Bl,
    int lda, int ldb, int rowBlock, int colBlock, int kmax,
    f32x4 (&acc)[4][4])
{
  __shared__ __align__(16) u16 Als[SPLIT ? 2 : 1][128 * 32];
  __shared__ __align__(16) u16 Bls[SPLIT ? 2 : 1][128 * 32];
  const int tid  = threadIdx.x;
  const int wid  = tid >> 6;
  const int lane = tid & 63;
  const int wr   = (wid & 1) << 6;       // wave row quadrant
  const int wc   = (wid >> 1) << 6;      // wave col quadrant
  const int lrow = lane & 15;            // A/B fragment row (m or n)
  const int lk   = (lane >> 4) << 3;     // fragment k base: quad*8
  const int srow = wid * 32 + (lane >> 2);   // staging row within 128-tile
  const int skol = (lane & 3) << 3;          // staging k offset (8 elems = 16 B)

  const f32x4 zero = {0.f, 0.f, 0.f, 0.f};
#pragma unroll
  for (int i = 0; i < 4; ++i)
#pragma unroll
    for (int j = 0; j < 4; ++j) acc[i][j] = zero;

  for (int kb = 0; kb < kmax; kb += 32) {
#pragma unroll
    for (int t = 0; t < 2; ++t) {
      const size_t ga = (size_t)(rowBlock + srow + t * 16) * lda + kb + skol;
      const size_t gb = (size_t)(colBlock + srow + t * 16) * ldb + kb + skol;
      const int lo = (wid * 32 + t * 16) * 32;   // wave-uniform LDS base
      g2l16(Ah + ga, &Als[0][lo]);
      g2l16(Bh + gb, &Bls[0][lo]);
      if constexpr (SPLIT) {
        g2l16(Al + ga, &Als[1][lo]);
        g2l16(Bl + gb, &Bls[1][lo]);
      }
    }
    __syncthreads();

    bf16x8 ah[4], bh[4], al[4], bl[4];
#pragma unroll
    for (int r = 0; r < 4; ++r) {
      ah[r] = *(const bf16x8*)&Als[0][(wr + r * 16 + lrow) * 32 + lk];
      bh[r] = *(const bf16x8*)&Bls[0][(wc + r * 16 + lrow) * 32 + lk];
      if constexpr (SPLIT) {
        al[r] = *(const bf16x8*)&Als[1][(wr + r * 16 + lrow) * 32 + lk];
        bl[r] = *(const bf16x8*)&Bls[1][(wc + r * 16 + lrow) * 32 + lk];
      }
    }
#pragma unroll
    for (int r = 0; r < 4; ++r)
#pragma unroll
      for (int c = 0; c < 4; ++c) {
        acc[r][c] = MFMA16(ah[r], bh[c], acc[r][c]);
        if constexpr (SPLIT) {
          acc[r][c] = MFMA16(ah[r], bl[c], acc[r][c]);
          acc[r][c] = MFMA16(al[r], bh[c], acc[r][c]);
        }
      }
    __syncthreads();
  }
}

// ---------------- split/transpose preprocessing ----------------
__global__ __launch_bounds__(256) void k_split_x(const float* __restrict__ X,
                                                 u16* __restrict__ Xh, u16* __restrict__ Xl) {
  const size_t i = ((size_t)blockIdx.x * 256 + threadIdx.x) * 4;
  const float4 v = *(const float4*)(X + i);
  ushort4 h, l;
  h.x = f2bf(v.x); l.x = f2bf(v.x - bf2f(h.x));
  h.y = f2bf(v.y); l.y = f2bf(v.y - bf2f(h.y));
  h.z = f2bf(v.z); l.z = f2bf(v.z - bf2f(h.z));
  h.w = f2bf(v.w); l.w = f2bf(v.w - bf2f(h.w));
  *(ushort4*)(Xh + i) = h;
  *(ushort4*)(Xl + i) = l;
}

// W [K][N] fp32 -> Wt hi/lo [N][K] bf16 (z=2: Wv, hi only)
__global__ __launch_bounds__(256) void k_split_w(
    const float* __restrict__ Wq, const float* __restrict__ Wk, const float* __restrict__ Wv,
    u16* __restrict__ Wqh, u16* __restrict__ Wql,
    u16* __restrict__ Wkh, u16* __restrict__ Wkl, u16* __restrict__ Wvh) {
  const int z = blockIdx.z;
  const float* W = (z == 0) ? Wq : (z == 1) ? Wk : Wv;
  u16* Oh = (z == 0) ? Wqh : (z == 1) ? Wkh : Wvh;
  u16* Ol = (z == 0) ? Wql : Wkl;
  __shared__ float t[32][33];
  const int tx = threadIdx.x & 31, ty = threadIdx.x >> 5;
  const int n0 = blockIdx.x * 32, k0 = blockIdx.y * 32;
#pragma unroll
  for (int i = 0; i < 4; ++i)
    t[ty + i * 8][tx] = W[(size_t)(k0 + ty + i * 8) * DM + n0 + tx];
  __syncthreads();
#pragma unroll
  for (int i = 0; i < 4; ++i) {
    const int n = ty + i * 8;
    const float v = t[tx][n];
    const u16 h = f2bf(v);
    const size_t off = (size_t)(n0 + n) * DM + k0 + tx;
    Oh[off] = h;
    if (z < 2) Ol[off] = f2bf(v - bf2f(h));
  }
}

// ---------------- GEMM kernels ----------------
// Q/K projections (bf16x3). Q gets 1/sqrt(2048) folded in; outputs hi/lo planes.
__global__ __launch_bounds__(256) void k_proj_qk(
    const u16* __restrict__ Xh, const u16* __restrict__ Xl,
    const u16* __restrict__ Wqh, const u16* __restrict__ Wql,
    const u16* __restrict__ Wkh, const u16* __restrict__ Wkl,
    u16* __restrict__ Qh, u16* __restrict__ Ql,
    u16* __restrict__ Kh, u16* __restrict__ Kl, float rscaleQ)
{
  const int z = blockIdx.z;
  const u16* Bh = z ? Wkh : Wqh;
  const u16* Bl = z ? Wkl : Wql;
  u16* Oh = z ? Kh : Qh;
  u16* Ol = z ? Kl : Ql;
  const float rs = z ? 1.0f : rscaleQ;
  f32x4 acc[4][4];
  gemm_core<true>(Xh, Xl, Bh, Bl, DM, DM, blockIdx.y * 128, blockIdx.x * 128, DM, acc);

  const int lane = threadIdx.x & 63, wid = threadIdx.x >> 6;
  const int r0 = blockIdx.y * 128 + ((wid & 1) << 6) + ((lane >> 4) << 2);
  const int c0 = blockIdx.x * 128 + ((wid >> 1) << 6) + (lane & 15);
#pragma unroll
  for (int r = 0; r < 4; ++r)
#pragma unroll
    for (int c = 0; c < 4; ++c) {
      const int col = c0 + c * 16;
#pragma unroll
      for (int e = 0; e < 4; ++e) {
        const float v = acc[r][c][e] * rs;
        const u16 h = f2bf(v);
        const size_t off = (size_t)(r0 + r * 16 + e) * DM + col;
        Oh[off] = h;
        Ol[off] = f2bf(v - bf2f(h));
      }
    }
}

// V projection (plain bf16), stores transposed Vt[d][s] bf16.
__global__ __launch_bounds__(256) void k_proj_v(
    const u16* __restrict__ Xh, const u16* __restrict__ Wvh, u16* __restrict__ Vt)
{
  f32x4 acc[4][4];
  gemm_core<false>(Xh, nullptr, Wvh, nullptr, DM, DM, blockIdx.y * 128, blockIdx.x * 128, DM, acc);

  const int lane = threadIdx.x & 63, wid = threadIdx.x >> 6;
  const int r0 = blockIdx.y * 128 + ((wid & 1) << 6) + ((lane >> 4) << 2);
  const int c0 = blockIdx.x * 128 + ((wid >> 1) << 6) + (lane & 15);
#pragma unroll
  for (int r = 0; r < 4; ++r)
#pragma unroll
    for (int c = 0; c < 4; ++c) {
      const int d = c0 + c * 16;
      const int s0 = r0 + r * 16;
      ushort4 pk;
      pk.x = f2bf(acc[r][c][0]); pk.y = f2bf(acc[r][c][1]);
      pk.z = f2bf(acc[r][c][2]); pk.w = f2bf(acc[r][c][3]);
      *(ushort4*)(Vt + (size_t)d * SEQ + s0) = pk;
    }
}

// S = (Q/scale) @ K^T (bf16x3), lower-triangular 128-blocks only, fp32 out.
__global__ __launch_bounds__(256) void k_scores(
    const u16* __restrict__ Qh, const u16* __restrict__ Ql,
    const u16* __restrict__ Kh, const u16* __restrict__ Kl, float* __restrict__ S)
{
  if (blockIdx.x > blockIdx.y) return;
  f32x4 acc[4][4];
  gemm_core<true>(Qh, Ql, Kh, Kl, DM, DM, blockIdx.y * 128, blockIdx.x * 128, DM, acc);

  const int lane = threadIdx.x & 63, wid = threadIdx.x >> 6;
  const int r0 = blockIdx.y * 128 + ((wid & 1) << 6) + ((lane >> 4) << 2);
  const int c0 = blockIdx.x * 128 + ((wid >> 1) << 6) + (lane & 15);
#pragma unroll
  for (int r = 0; r < 4; ++r)
#pragma unroll
    for (int c = 0; c < 4; ++c)
#pragma unroll
      for (int e = 0; e < 4; ++e)
        S[(size_t)(r0 + r * 16 + e) * SEQ + (c0 + c * 16)] = acc[r][c][e];
}

// Row softmax (causal) + inverted dropout; S fp32 -> P bf16 (zero-padded to 128).
__global__ __launch_bounds__(256) void k_softmax_dropout(const float* __restrict__ S,
                                                         u16* __restrict__ P) {
  const int row = blockIdx.x;
  const int n = row + 1;
  const int tid = threadIdx.x;
  __shared__ float buf[SEQ];
  __shared__ float red[4];
  __shared__ float bcast;
  const float* srow = S + (size_t)row * SEQ;

  float lmax = -INFINITY;
#pragma unroll
  for (int t = 0; t < 4; ++t) {
    int j4 = tid + t * 256;
    float4 v = *(const float4*)(srow + (size_t)j4 * 4);
    int b = j4 * 4;
    float x0 = (b + 0 < n) ? v.x : -INFINITY;
    float x1 = (b + 1 < n) ? v.y : -INFINITY;
    float x2 = (b + 2 < n) ? v.z : -INFINITY;
    float x3 = (b + 3 < n) ? v.w : -INFINITY;
    buf[b + 0] = x0; buf[b + 1] = x1; buf[b + 2] = x2; buf[b + 3] = x3;
    lmax = fmaxf(lmax, fmaxf(fmaxf(x0, x1), fmaxf(x2, x3)));
  }
  for (int off = 32; off > 0; off >>= 1) lmax = fmaxf(lmax, __shfl_down(lmax, off, 64));
  if ((tid & 63) == 0) red[tid >> 6] = lmax;
  __syncthreads();
  if (tid == 0) bcast = fmaxf(fmaxf(red[0], red[1]), fmaxf(red[2], red[3]));
  __syncthreads();
  const float m = bcast;

  float lsum = 0.f;
#pragma unroll
  for (int t = 0; t < 4; ++t) {
    int b = (tid + t * 256) * 4;
    float e0 = expf(buf[b + 0] - m);
    float e1 = expf(buf[b + 1] - m);
    float e2 = expf(buf[b + 2] - m);
    float e3 = expf(buf[b + 3] - m);
    buf[b + 0] = e0; buf[b + 1] = e1; buf[b + 2] = e2; buf[b + 3] = e3;
    lsum += (e0 + e1) + (e2 + e3);
  }
  for (int off = 32; off > 0; off >>= 1) lsum += __shfl_down(lsum, off, 64);
  if ((tid & 63) == 0) red[tid >> 6] = lsum;
  __syncthreads();
  if (tid == 0) bcast = (red[0] + red[1]) + (red[2] + red[3]);
  __syncthreads();
  const float total = bcast;

  u16* prow = P + (size_t)row * SEQ;
  const int zeroEnd = ((row >> 7) + 1) << 7;
  for (int j = tid; j < zeroEnd; j += 256) {
    float out = 0.f;
    if (j < n) {
      const float w = buf[j] / total;
      out = dropout_keep((u32)(row * SEQ + j)) ? w * 2.0f : 0.f;
    }
    prow[j] = f2bf(out);
  }
}

// context = P @ V (plain bf16, causal-truncated K-loop), fp32 out.
__global__ __launch_bounds__(256) void k_pv(const u16* __restrict__ P,
                                            const u16* __restrict__ Vt,
                                            float* __restrict__ O) {
  const int by = blockIdx.y;
  f32x4 acc[4][4];
  gemm_core<false>(P, nullptr, Vt, nullptr, SEQ, SEQ, by * 128, blockIdx.x * 128,
                   (by + 1) * 128, acc);

  const int lane = threadIdx.x & 63, wid = threadIdx.x >> 6;
  const int r0 = by * 128 + ((wid & 1) << 6) + ((lane >> 4) << 2);
  const int c0 = blockIdx.x * 128 + ((wid >> 1) << 6) + (lane & 15);
#pragma unroll
  for (int r = 0; r < 4; ++r)
#pragma unroll
    for (int c = 0; c < 4; ++c)
#pragma unroll
      for (int e = 0; e < 4; ++e)
        O[(size_t)(r0 + r * 16 + e) * DM + (c0 + c * 16)] = acc[r][c][e];
}

extern "C" void kernel_launch(void* const* d_in, const int* in_sizes, int n_in,
                              void* d_out, int out_size, void* d_ws, size_t ws_size,
                              hipStream_t stream) {
  const float* x  = (const float*)d_in[0];
  const float* Wq = (const float*)d_in[1];
  const float* Wk = (const float*)d_in[2];
  const float* Wv = (const float*)d_in[3];

  // workspace layout (u16 elements; 152 MiB total, round 1 proved >=160 MiB)
  const size_t PL = (size_t)SEQ * DM;   // 8.4M elems = 16 MiB/plane
  const size_t WL = (size_t)DM * DM;    // 4.2M elems = 8 MiB/plane
  u16* base = (u16*)d_ws;
  u16* Qh = base;                // [SEQ][DM]
  u16* Ql = Qh + PL;
  u16* Kh = Ql + PL;
  u16* Kl = Kh + PL;
  u16* Vt = Kl + PL;             // [DM][SEQ]
  u16* P  = base;                // [SEQ][SEQ] bf16, overlays Qh+Ql (dead by then)
  u16* regA = Vt + PL;           // offset 80 MiB
  u16* Xh  = regA;               // [SEQ][DM]
  u16* Xl  = Xh + PL;
  u16* Wqh = Xl + PL;            // [DM][DM] transposed
  u16* Wql = Wqh + WL;
  u16* Wkh = Wql + WL;
  u16* Wkl = Wkh + WL;
  u16* Wvh = Wkl + WL;
  float* S = (float*)regA;       // [SEQ][SEQ] fp32, overlays X/W splits (dead by then)

  const float rscale = 1.0f / sqrtf(2048.0f);
  dim3 blk(256);
  k_split_x<<<dim3((unsigned)(PL / 1024)), blk, 0, stream>>>(x, Xh, Xl);
  k_split_w<<<dim3(DM / 32, DM / 32, 3), blk, 0, stream>>>(Wq, Wk, Wv, Wqh, Wql, Wkh, Wkl, Wvh);
  k_proj_qk<<<dim3(DM / 128, SEQ / 128, 2), blk, 0, stream>>>(Xh, Xl, Wqh, Wql, Wkh, Wkl,
                                                              Qh, Ql, Kh, Kl, rscale);
  k_proj_v<<<dim3(DM / 128, SEQ / 128), blk, 0, stream>>>(Xh, Wvh, Vt);
  k_scores<<<dim3(SEQ / 128, SEQ / 128), blk, 0, stream>>>(Qh, Ql, Kh, Kl, S);
  k_softmax_dropout<<<dim3(SEQ), blk, 0, stream>>>(S, P);
  k_pv<<<dim3(DM / 128, SEQ / 128), blk, 0, stream>>>(P, Vt, (float*)d_out);
}

// Round 3
// 661.288 us; speedup vs baseline: 3.9188x; 1.0651x over previous
//
#include <hip/hip_runtime.h>
#include <cstdint>
#include <cstddef>
#include <cmath>

#define SEQ 4096
#define DM  2048

typedef unsigned int u32;
typedef unsigned short u16;
typedef __attribute__((ext_vector_type(8))) short bf16x8;
typedef __attribute__((ext_vector_type(4))) float f32x4;

// ---------------- bf16 helpers (RNE) ----------------
__device__ __forceinline__ u16 f2bf(float f) {
  u32 u = __float_as_uint(f);
  return (u16)((u + 0x7FFFu + ((u >> 16) & 1u)) >> 16);
}
__device__ __forceinline__ float bf2f(u16 h) { return __uint_as_float(((u32)h) << 16); }

// ---------------- threefry dropout (verified round 1, variant 0) ----------------
__device__ __forceinline__ u32 rotl32(u32 x, int r) { return (x << r) | (x >> (32 - r)); }

__device__ __forceinline__ void tf2x32(u32 c0, u32 c1, u32& o0, u32& o1) {
  const u32 k0 = 0u, k1 = 42u, k2 = 0x1BD11BDAu ^ 0u ^ 42u;
  u32 x0 = c0 + k0;
  u32 x1 = c1 + k1;
#define TFR(r) { x0 += x1; x1 = rotl32(x1, (r)); x1 ^= x0; }
  TFR(13) TFR(15) TFR(26) TFR(6)   x0 += k1; x1 += k2 + 1u;
  TFR(17) TFR(29) TFR(16) TFR(24)  x0 += k2; x1 += k0 + 2u;
  TFR(13) TFR(15) TFR(26) TFR(6)   x0 += k0; x1 += k1 + 3u;
  TFR(17) TFR(29) TFR(16) TFR(24)  x0 += k1; x1 += k2 + 4u;
  TFR(13) TFR(15) TFR(26) TFR(6)   x0 += k2; x1 += k0 + 5u;
#undef TFR
  o0 = x0; o1 = x1;
}

__device__ __forceinline__ bool dropout_keep(u32 idx) {
  u32 a, b; tf2x32(0u, idx, a, b);
  return (((a ^ b) & 0x80000000u) == 0u);
}

// ---------------- async global -> LDS, 16 B/lane ----------------
__device__ __forceinline__ void g2l16(const void* g, void* l) {
  __builtin_amdgcn_global_load_lds((const __attribute__((address_space(1))) u32*)g,
                                   (__attribute__((address_space(3))) u32*)l, 16, 0, 0);
}

#define MFMA16(a, b, c) __builtin_amdgcn_mfma_f32_16x16x32_bf16(a, b, c, 0, 0, 0)

// ---------------------------------------------------------------------------
// MFMA GEMM core: C[128x128] = A * B^T, both operands [row][k] bf16, k contig.
// SPLIT: fp32 emulation via hi/lo planes (3 MFMAs per fragment pair).
// LDS k-chunk XOR swizzle: slot (row, c) holds global 16B-chunk c ^ ((row>>1)&3).
// -> staging stays contiguous (global_load_lds constraint), fragment reads hit
//    each 4-bank group exactly 2x per 16-lane cohort (2-way = free, m136),
//    killing the 8-way conflict of the unswizzled row*64B layout.
// ---------------------------------------------------------------------------
template <bool SPLIT>
__device__ __forceinline__ void gemm_core(
    const u16* __restrict__ Ah, const u16* __restrict__ Al,
    const u16* __restrict__ Bh, const u16* __restrict__ Bl,
    int lda, int ldb, int rowBlock, int colBlock, int kmax,
    f32x4 (&acc)[4][4])
{
  __shared__ __align__(16) u16 Als[SPLIT ? 2 : 1][128 * 32];
  __shared__ __align__(16) u16 Bls[SPLIT ? 2 : 1][128 * 32];
  const int tid  = threadIdx.x;
  const int wid  = tid >> 6;
  const int lane = tid & 63;
  const int wr   = (wid & 1) << 6;       // wave row quadrant
  const int wc   = (wid >> 1) << 6;      // wave col quadrant
  const int lrow = lane & 15;            // fragment row within 16-tile
  // swizzled fragment k-offset: chunk = (lane>>4) ^ ((row>>1)&3); row%16==lrow
  const int lk   = (((lane >> 4) ^ ((lrow >> 1) & 3)) << 3);
  const int srow = wid * 32 + (lane >> 2);              // staging row in 128-tile
  // swizzled staging source chunk: c ^ ((srow>>1)&3) = (lane&3) ^ ((lane>>3)&3)
  const int skol = (((lane & 3) ^ ((lane >> 3) & 3)) << 3);

  const f32x4 zero = {0.f, 0.f, 0.f, 0.f};
#pragma unroll
  for (int i = 0; i < 4; ++i)
#pragma unroll
    for (int j = 0; j < 4; ++j) acc[i][j] = zero;

  for (int kb = 0; kb < kmax; kb += 32) {
#pragma unroll
    for (int t = 0; t < 2; ++t) {
      const size_t ga = (size_t)(rowBlock + srow + t * 16) * lda + kb + skol;
      const size_t gb = (size_t)(colBlock + srow + t * 16) * ldb + kb + skol;
      const int lo = (wid * 32 + t * 16) * 32;   // wave-uniform LDS base
      g2l16(Ah + ga, &Als[0][lo]);
      g2l16(Bh + gb, &Bls[0][lo]);
      if constexpr (SPLIT) {
        g2l16(Al + ga, &Als[1][lo]);
        g2l16(Bl + gb, &Bls[1][lo]);
      }
    }
    __syncthreads();

    bf16x8 ah[4], bh[4], al[4], bl[4];
#pragma unroll
    for (int r = 0; r < 4; ++r) {
      ah[r] = *(const bf16x8*)&Als[0][(wr + r * 16 + lrow) * 32 + lk];
      bh[r] = *(const bf16x8*)&Bls[0][(wc + r * 16 + lrow) * 32 + lk];
      if constexpr (SPLIT) {
        al[r] = *(const bf16x8*)&Als[1][(wr + r * 16 + lrow) * 32 + lk];
        bl[r] = *(const bf16x8*)&Bls[1][(wc + r * 16 + lrow) * 32 + lk];
      }
    }
#pragma unroll
    for (int r = 0; r < 4; ++r)
#pragma unroll
      for (int c = 0; c < 4; ++c) {
        acc[r][c] = MFMA16(ah[r], bh[c], acc[r][c]);
        if constexpr (SPLIT) {
          acc[r][c] = MFMA16(ah[r], bl[c], acc[r][c]);
          acc[r][c] = MFMA16(al[r], bh[c], acc[r][c]);
        }
      }
    __syncthreads();
  }
}

// ---------------- split/transpose preprocessing ----------------
__global__ __launch_bounds__(256) void k_split_x(const float* __restrict__ X,
                                                 u16* __restrict__ Xh, u16* __restrict__ Xl) {
  const size_t i = ((size_t)blockIdx.x * 256 + threadIdx.x) * 4;
  const float4 v = *(const float4*)(X + i);
  ushort4 h, l;
  h.x = f2bf(v.x); l.x = f2bf(v.x - bf2f(h.x));
  h.y = f2bf(v.y); l.y = f2bf(v.y - bf2f(h.y));
  h.z = f2bf(v.z); l.z = f2bf(v.z - bf2f(h.z));
  h.w = f2bf(v.w); l.w = f2bf(v.w - bf2f(h.w));
  *(ushort4*)(Xh + i) = h;
  *(ushort4*)(Xl + i) = l;
}

// W [K][N] fp32 -> Wt hi/lo [N][K] bf16 (z=2: Wv, hi only)
__global__ __launch_bounds__(256) void k_split_w(
    const float* __restrict__ Wq, const float* __restrict__ Wk, const float* __restrict__ Wv,
    u16* __restrict__ Wqh, u16* __restrict__ Wql,
    u16* __restrict__ Wkh, u16* __restrict__ Wkl, u16* __restrict__ Wvh) {
  const int z = blockIdx.z;
  const float* W = (z == 0) ? Wq : (z == 1) ? Wk : Wv;
  u16* Oh = (z == 0) ? Wqh : (z == 1) ? Wkh : Wvh;
  u16* Ol = (z == 0) ? Wql : Wkl;
  __shared__ float t[32][33];
  const int tx = threadIdx.x & 31, ty = threadIdx.x >> 5;
  const int n0 = blockIdx.x * 32, k0 = blockIdx.y * 32;
#pragma unroll
  for (int i = 0; i < 4; ++i)
    t[ty + i * 8][tx] = W[(size_t)(k0 + ty + i * 8) * DM + n0 + tx];
  __syncthreads();
#pragma unroll
  for (int i = 0; i < 4; ++i) {
    const int n = ty + i * 8;
    const float v = t[tx][n];
    const u16 h = f2bf(v);
    const size_t off = (size_t)(n0 + n) * DM + k0 + tx;
    Oh[off] = h;
    if (z < 2) Ol[off] = f2bf(v - bf2f(h));
  }
}

// ---------------- GEMM kernels ----------------
// Q/K projections (bf16x3). Q gets 1/sqrt(2048) folded in; outputs hi/lo planes.
__global__ __launch_bounds__(256) void k_proj_qk(
    const u16* __restrict__ Xh, const u16* __restrict__ Xl,
    const u16* __restrict__ Wqh, const u16* __restrict__ Wql,
    const u16* __restrict__ Wkh, const u16* __restrict__ Wkl,
    u16* __restrict__ Qh, u16* __restrict__ Ql,
    u16* __restrict__ Kh, u16* __restrict__ Kl, float rscaleQ)
{
  const int z = blockIdx.z;
  const u16* Bh = z ? Wkh : Wqh;
  const u16* Bl = z ? Wkl : Wql;
  u16* Oh = z ? Kh : Qh;
  u16* Ol = z ? Kl : Ql;
  const float rs = z ? 1.0f : rscaleQ;
  f32x4 acc[4][4];
  gemm_core<true>(Xh, Xl, Bh, Bl, DM, DM, blockIdx.y * 128, blockIdx.x * 128, DM, acc);

  const int lane = threadIdx.x & 63, wid = threadIdx.x >> 6;
  const int r0 = blockIdx.y * 128 + ((wid & 1) << 6) + ((lane >> 4) << 2);
  const int c0 = blockIdx.x * 128 + ((wid >> 1) << 6) + (lane & 15);
#pragma unroll
  for (int r = 0; r < 4; ++r)
#pragma unroll
    for (int c = 0; c < 4; ++c) {
      const int col = c0 + c * 16;
#pragma unroll
      for (int e = 0; e < 4; ++e) {
        const float v = acc[r][c][e] * rs;
        const u16 h = f2bf(v);
        const size_t off = (size_t)(r0 + r * 16 + e) * DM + col;
        Oh[off] = h;
        Ol[off] = f2bf(v - bf2f(h));
      }
    }
}

// V projection (plain bf16), stores transposed Vt[d][s] bf16.
__global__ __launch_bounds__(256) void k_proj_v(
    const u16* __restrict__ Xh, const u16* __restrict__ Wvh, u16* __restrict__ Vt)
{
  f32x4 acc[4][4];
  gemm_core<false>(Xh, nullptr, Wvh, nullptr, DM, DM, blockIdx.y * 128, blockIdx.x * 128, DM, acc);

  const int lane = threadIdx.x & 63, wid = threadIdx.x >> 6;
  const int r0 = blockIdx.y * 128 + ((wid & 1) << 6) + ((lane >> 4) << 2);
  const int c0 = blockIdx.x * 128 + ((wid >> 1) << 6) + (lane & 15);
#pragma unroll
  for (int r = 0; r < 4; ++r)
#pragma unroll
    for (int c = 0; c < 4; ++c) {
      const int d = c0 + c * 16;
      const int s0 = r0 + r * 16;
      ushort4 pk;
      pk.x = f2bf(acc[r][c][0]); pk.y = f2bf(acc[r][c][1]);
      pk.z = f2bf(acc[r][c][2]); pk.w = f2bf(acc[r][c][3]);
      *(ushort4*)(Vt + (size_t)d * SEQ + s0) = pk;
    }
}

// S = (Q/scale) @ K^T (bf16x3), exactly the 528 lower-triangular blocks.
__global__ __launch_bounds__(256) void k_scores(
    const u16* __restrict__ Qh, const u16* __restrict__ Ql,
    const u16* __restrict__ Kh, const u16* __restrict__ Kl, float* __restrict__ S)
{
  const int bid = blockIdx.x;
  int by = (int)((sqrtf(8.0f * (float)bid + 1.0f) - 1.0f) * 0.5f);
  while ((by + 1) * (by + 2) / 2 <= bid) ++by;
  while (by * (by + 1) / 2 > bid) --by;
  const int bx = bid - by * (by + 1) / 2;

  f32x4 acc[4][4];
  gemm_core<true>(Qh, Ql, Kh, Kl, DM, DM, by * 128, bx * 128, DM, acc);

  const int lane = threadIdx.x & 63, wid = threadIdx.x >> 6;
  const int r0 = by * 128 + ((wid & 1) << 6) + ((lane >> 4) << 2);
  const int c0 = bx * 128 + ((wid >> 1) << 6) + (lane & 15);
#pragma unroll
  for (int r = 0; r < 4; ++r)
#pragma unroll
    for (int c = 0; c < 4; ++c)
#pragma unroll
      for (int e = 0; e < 4; ++e)
        S[(size_t)(r0 + r * 16 + e) * SEQ + (c0 + c * 16)] = acc[r][c][e];
}

// Row softmax (causal) + inverted dropout; S fp32 -> P bf16 (zero-padded to 128).
// Only touches the 1024-wide tiles that contain valid entries.
__global__ __launch_bounds__(256) void k_softmax_dropout(const float* __restrict__ S,
                                                         u16* __restrict__ P) {
  const int row = blockIdx.x;
  const int n = row + 1;
  const int nt = (n + 1023) >> 10;   // 1..4 tiles of 1024 columns
  const int tid = threadIdx.x;
  __shared__ float buf[SEQ];
  __shared__ float red[4];
  __shared__ float bcast;
  const float* srow = S + (size_t)row * SEQ;

  float lmax = -INFINITY;
  for (int t = 0; t < nt; ++t) {
    int j4 = tid + t * 256;
    float4 v = *(const float4*)(srow + (size_t)j4 * 4);
    int b = j4 * 4;
    float x0 = (b + 0 < n) ? v.x : -INFINITY;
    float x1 = (b + 1 < n) ? v.y : -INFINITY;
    float x2 = (b + 2 < n) ? v.z : -INFINITY;
    float x3 = (b + 3 < n) ? v.w : -INFINITY;
    buf[b + 0] = x0; buf[b + 1] = x1; buf[b + 2] = x2; buf[b + 3] = x3;
    lmax = fmaxf(lmax, fmaxf(fmaxf(x0, x1), fmaxf(x2, x3)));
  }
  for (int off = 32; off > 0; off >>= 1) lmax = fmaxf(lmax, __shfl_down(lmax, off, 64));
  if ((tid & 63) == 0) red[tid >> 6] = lmax;
  __syncthreads();
  if (tid == 0) bcast = fmaxf(fmaxf(red[0], red[1]), fmaxf(red[2], red[3]));
  __syncthreads();
  const float m = bcast;

  float lsum = 0.f;
  for (int t = 0; t < nt; ++t) {
    int b = (tid + t * 256) * 4;
    float e0 = expf(buf[b + 0] - m);
    float e1 = expf(buf[b + 1] - m);
    float e2 = expf(buf[b + 2] - m);
    float e3 = expf(buf[b + 3] - m);
    buf[b + 0] = e0; buf[b + 1] = e1; buf[b + 2] = e2; buf[b + 3] = e3;
    lsum += (e0 + e1) + (e2 + e3);
  }
  for (int off = 32; off > 0; off >>= 1) lsum += __shfl_down(lsum, off, 64);
  if ((tid & 63) == 0) red[tid >> 6] = lsum;
  __syncthreads();
  if (tid == 0) bcast = (red[0] + red[1]) + (red[2] + red[3]);
  __syncthreads();
  const float total = bcast;

  u16* prow = P + (size_t)row * SEQ;
  const int zeroEnd = ((row >> 7) + 1) << 7;
  for (int j = tid; j < zeroEnd; j += 256) {
    float out = 0.f;
    if (j < n) {
      const float w = buf[j] / total;
      out = dropout_keep((u32)(row * SEQ + j)) ? w * 2.0f : 0.f;
    }
    prow[j] = f2bf(out);
  }
}

// context = P @ V (plain bf16, causal-truncated K-loop), fp32 out.
// Heavy rows (large by) scheduled first to shrink the load-imbalance tail.
__global__ __launch_bounds__(256) void k_pv(const u16* __restrict__ P,
                                            const u16* __restrict__ Vt,
                                            float* __restrict__ O) {
  const int by = (SEQ / 128 - 1) - blockIdx.y;
  f32x4 acc[4][4];
  gemm_core<false>(P, nullptr, Vt, nullptr, SEQ, SEQ, by * 128, blockIdx.x * 128,
                   (by + 1) * 128, acc);

  const int lane = threadIdx.x & 63, wid = threadIdx.x >> 6;
  const int r0 = by * 128 + ((wid & 1) << 6) + ((lane >> 4) << 2);
  const int c0 = blockIdx.x * 128 + ((wid >> 1) << 6) + (lane & 15);
#pragma unroll
  for (int r = 0; r < 4; ++r)
#pragma unroll
    for (int c = 0; c < 4; ++c)
#pragma unroll
      for (int e = 0; e < 4; ++e)
        O[(size_t)(r0 + r * 16 + e) * DM + (c0 + c * 16)] = acc[r][c][e];
}

extern "C" void kernel_launch(void* const* d_in, const int* in_sizes, int n_in,
                              void* d_out, int out_size, void* d_ws, size_t ws_size,
                              hipStream_t stream) {
  const float* x  = (const float*)d_in[0];
  const float* Wq = (const float*)d_in[1];
  const float* Wk = (const float*)d_in[2];
  const float* Wv = (const float*)d_in[3];

  // workspace layout (u16 elements; 152 MiB total)
  const size_t PL = (size_t)SEQ * DM;   // 8.4M elems = 16 MiB/plane
  const size_t WL = (size_t)DM * DM;    // 4.2M elems = 8 MiB/plane
  u16* base = (u16*)d_ws;
  u16* Qh = base;                // [SEQ][DM]
  u16* Ql = Qh + PL;
  u16* Kh = Ql + PL;
  u16* Kl = Kh + PL;
  u16* Vt = Kl + PL;             // [DM][SEQ]
  u16* P  = base;                // [SEQ][SEQ] bf16, overlays Qh+Ql (dead by then)
  u16* regA = Vt + PL;           // offset 80 MiB
  u16* Xh  = regA;               // [SEQ][DM]
  u16* Xl  = Xh + PL;
  u16* Wqh = Xl + PL;            // [DM][DM] transposed
  u16* Wql = Wqh + WL;
  u16* Wkh = Wql + WL;
  u16* Wkl = Wkh + WL;
  u16* Wvh = Wkl + WL;
  float* S = (float*)regA;       // [SEQ][SEQ] fp32, overlays X/W splits (dead by then)

  const float rscale = 1.0f / sqrtf(2048.0f);
  dim3 blk(256);
  k_split_x<<<dim3((unsigned)(PL / 1024)), blk, 0, stream>>>(x, Xh, Xl);
  k_split_w<<<dim3(DM / 32, DM / 32, 3), blk, 0, stream>>>(Wq, Wk, Wv, Wqh, Wql, Wkh, Wkl, Wvh);
  k_proj_qk<<<dim3(DM / 128, SEQ / 128, 2), blk, 0, stream>>>(Xh, Xl, Wqh, Wql, Wkh, Wkl,
                                                              Qh, Ql, Kh, Kl, rscale);
  k_proj_v<<<dim3(DM / 128, SEQ / 128), blk, 0, stream>>>(Xh, Wvh, Vt);
  k_scores<<<dim3((SEQ / 128) * (SEQ / 128 + 1) / 2), blk, 0, stream>>>(Qh, Ql, Kh, Kl, S);
  k_softmax_dropout<<<dim3(SEQ), blk, 0, stream>>>(S, P);
  k_pv<<<dim3(DM / 128, SEQ / 128), blk, 0, stream>>>(P, Vt, (float*)d_out);
}